// Round 7
// baseline (473.059 us; speedup 1.0000x reference)
//
#include <hip/hip_runtime.h>
#include <math.h>

#define TOK 8192   // B*S tokens
#define DIM 256    // hidden
#define NE  32     // experts
#define NK  4      // top-k
#define NF  1024   // ffn dim

typedef __bf16 bf16x8 __attribute__((ext_vector_type(8)));
typedef float  f32x4  __attribute__((ext_vector_type(4)));

__device__ __forceinline__ unsigned short f2b(float f) {
  unsigned u = __builtin_bit_cast(unsigned, f);
  unsigned r = (u + 0x7FFFu + ((u >> 16) & 1u)) >> 16;   // RNE
  return (unsigned short)r;
}

// async global->LDS, 16B per lane (global_load_lds_dwordx4)
__device__ __forceinline__ void gload_lds16(const void* g, void* l) {
  __builtin_amdgcn_global_load_lds(
      (const __attribute__((address_space(1))) unsigned int*)g,
      (__attribute__((address_space(3))) unsigned int*)l, 16, 0, 0);
}

// ================= fused router + weight-convert =================
// blocks [0,256): router (32 tokens each). blocks [256, 256+3*2048): cvt.
// Gate/up bf16 DRAM layout (swizzle baked; linear copy to LDS stays swizzled):
//   ushort (e*NF+f)*256 + ((gk ^ (f&7))<<3) + j   holds W[e][f][k=gk*8+j]
// Down bf16 layout: per (e,ch in 32): [256 d][32 f]:
//   ushort ((e*32+ch)*256 + d)*32 + ((fg ^ ((d>>1)&3))<<3) + j
//     holds Wd[e][d][ch*32 + fg*8 + j]
__global__ __launch_bounds__(256) void router_cvt_kernel(
    const float* __restrict__ x, const float* __restrict__ rw,
    const float* __restrict__ wg, const float* __restrict__ wu,
    const float* __restrict__ wd,
    int* __restrict__ counts, float* __restrict__ psum,
    int* __restrict__ etok, float* __restrict__ ewt,
    unsigned short* __restrict__ wgp, unsigned short* __restrict__ wup,
    unsigned short* __restrict__ wdp)
{
  __shared__ float xs[32][DIM + 4];
  __shared__ float ws[NE][DIM + 4];
  __shared__ float lg[32][NE];
  __shared__ int hist[NE];
  __shared__ int base[NE];

  const int tid = threadIdx.x;

  if (blockIdx.x >= 256) {
    // ---------- cvt branch ----------
    const int b2 = blockIdx.x - 256;
    const int sec = b2 >> 11;
    const int n4 = (int)((size_t)NE * NF * DIM / 4);
    const int stride = 2048 * 256;
    int i = (b2 & 2047) * 256 + tid;
    if (sec < 2) {
      const float* src = sec ? wu : wg;
      unsigned short* dst = sec ? wup : wgp;
      for (; i < n4; i += stride) {
        int k4 = i & 63, row = i >> 6;          // row = e*NF+f; row&7 == f&7
        int p = (k4 >> 1) ^ (row & 7);
        float4 v = ((const float4*)src)[i];
        ((ushort4*)dst)[((size_t)row << 6) + (p << 1) + (k4 & 1)] =
            make_ushort4(f2b(v.x), f2b(v.y), f2b(v.z), f2b(v.w));
      }
    } else {
      for (; i < n4; i += stride) {
        int j4 = i & 1, fg = (i >> 1) & 3, ch = (i >> 3) & 31;
        int d = (i >> 8) & 255, e = i >> 16;
        int s4 = (e * 256 + d) * 256 + ch * 8 + fg * 2 + j4;
        int p = fg ^ ((d >> 1) & 3);
        float4 v = ((const float4*)wd)[s4];
        ((ushort4*)wdp)[(size_t)(((e * 32 + ch) * 256 + d) * 8) + p * 2 + j4] =
            make_ushort4(f2b(v.x), f2b(v.y), f2b(v.z), f2b(v.w));
      }
    }
    return;
  }

  // ---------- router branch ----------
  const int t0 = blockIdx.x * 32;
  {
    const float4* xg = (const float4*)(x + (size_t)t0 * DIM);
    for (int i = tid; i < 32 * (DIM/4); i += 256) {
      int t = i / (DIM/4), c = i % (DIM/4);
      *(float4*)&xs[t][c*4] = xg[t*(DIM/4)+c];
    }
    const float4* wgq = (const float4*)rw;
    for (int i = tid; i < NE * (DIM/4); i += 256) {
      int e = i / (DIM/4), c = i % (DIM/4);
      *(float4*)&ws[e][c*4] = wgq[e*(DIM/4)+c];
    }
  }
  if (tid < NE) hist[tid] = 0;
  __syncthreads();

  for (int i = 0; i < 4; i++) {
    int idx = i*256 + tid;
    int t = idx >> 5, e = idx & 31;
    float acc = 0.f;
    for (int c = 0; c < DIM/4; c++) {
      float4 a = *(const float4*)&xs[t][c*4];
      float4 b = *(const float4*)&ws[e][c*4];
      acc += a.x*b.x + a.y*b.y + a.z*b.z + a.w*b.w;
    }
    lg[t][e] = acc;
  }
  __syncthreads();

  int ids[NK]; int slots[NK]; float wts[NK];
  if (tid < 32) {
    const int t = tid;
    float l[NE];
    #pragma unroll
    for (int e = 0; e < NE; e++) l[e] = lg[t][e];
    unsigned mask = 0;
    float vals[NK];
    #pragma unroll
    for (int k = 0; k < NK; k++) {
      float best = -INFINITY; int bi = 0;
      for (int e = 0; e < NE; e++)
        if (!((mask >> e) & 1u) && l[e] > best) { best = l[e]; bi = e; }
      mask |= 1u << bi; vals[k] = best; ids[k] = bi;
    }
    float s4 = 0.f;
    #pragma unroll
    for (int k = 0; k < NK; k++) { wts[k] = __expf(vals[k] - vals[0]); s4 += wts[k]; }
    #pragma unroll
    for (int k = 0; k < NK; k++) wts[k] /= s4;
    float s = 0.f;
    for (int e = 0; e < NE; e++) { l[e] = __expf(l[e] - vals[0]); s += l[e]; }
    float inv = 1.f / s;
    for (int e = 0; e < NE; e++) lg[t][e] = l[e] * inv;
    #pragma unroll
    for (int k = 0; k < NK; k++) slots[k] = atomicAdd(&hist[ids[k]], 1);
  }
  __syncthreads();
  if (tid < NE) {
    float s = 0.f;
    for (int t = 0; t < 32; t++) s += lg[t][tid];
    atomicAdd(&psum[tid], s);
    int h = hist[tid];
    base[tid] = h ? atomicAdd(&counts[tid], h) : 0;
  }
  __syncthreads();
  if (tid < 32) {
    #pragma unroll
    for (int k = 0; k < NK; k++) {
      int p = base[ids[k]] + slots[k];
      etok[(size_t)ids[k]*TOK + p] = t0 + tid;
      ewt [(size_t)ids[k]*TOK + p] = wts[k];
    }
  }
}

// ============ Expert FFN: bf16 pre-swizzled, DMA-staged, 3 blocks/CU ============
// 768 blocks x 256 thr (4 waves: mw=wv&1 32-token half, nw=wv>>1 f/d half).
// Block b: expert e=b&31 (XCD-pinned via e&7==b&7), slot s=b>>5 in [0,24).
// M=64 token tiles. 32-f chunks, phases G,U,D; 16KB ping-pong DMA stages.
// Latency hiding comes from 3 co-resident blocks per CU (m114 overlap).
__global__ __launch_bounds__(256, 3) void expert_mfma6_kernel(
    const float* __restrict__ x,
    const unsigned short* __restrict__ wgp,
    const unsigned short* __restrict__ wup,
    const unsigned short* __restrict__ wdp,
    const int* __restrict__ counts, const float* __restrict__ psum,
    const int* __restrict__ etok, const float* __restrict__ ewt,
    float* __restrict__ out)
{
  const int b = blockIdx.x;
  const int e = b & 31;
  const int s = b >> 5;          // 0..23
  const int cnt = counts[e];
  const int tid = threadIdx.x;

  // aux loss fold (block 0, wave 0)
  if (b == 0 && tid < 64) {
    float v = 0.f;
    if (tid < NE) v = (counts[tid] / (float)TOK) * (psum[tid] / (float)TOK);
    #pragma unroll
    for (int off = 32; off; off >>= 1) v += __shfl_down(v, off);
    if (tid == 0) out[(size_t)TOK * DIM] = (float)NE * v;
  }

  __shared__ unsigned short stg[2][8192];   // 2 x 16 KB DMA stages
  __shared__ unsigned short hs[64][40];     // 5.1 KB H tile (32 used + 8 pad)
  __shared__ int   lel[64];
  __shared__ float lwt[64];

  const int lane = tid & 63;
  const int wv   = tid >> 6;
  const int mw   = wv & 1;      // token half (32 tokens)
  const int nw   = wv >> 1;     // f-half (16 f) / d-half (128 d)
  const int q    = lane >> 4;
  const int ln   = lane & 15;

  const unsigned short* wgE = wgp + (size_t)e * NF * 256;
  const unsigned short* wuE = wup + (size_t)e * NF * 256;
  const unsigned short* wdE = wdp + (size_t)e * 32 * 8192;

  const int*   el = etok + (size_t)e * TOK;
  const float* ew = ewt  + (size_t)e * TOK;

  const int guOff = (nw*16 + ln) * 256;   // gate/up frag row base
  const int guXo  = (nw*16 + ln) & 7;     // gate/up XOR key

  for (int t0 = s * 64; t0 < cnt; t0 += 24 * 64) {
    if (tid < 64) {
      int gt = t0 + tid;
      lel[tid] = (gt < cnt) ? el[gt] : -1;
      lwt[tid] = (gt < cnt) ? ew[gt] : 0.f;
    }
    __syncthreads();

    // A-fragments: this wave's 32 tokens x K=256 (fp32->bf16, registers)
    bf16x8 xf[2][8];
    #pragma unroll
    for (int m = 0; m < 2; m++) {
      int tok = lel[mw*32 + m*16 + ln]; if (tok < 0) tok = 0;
      const float* xr = x + (size_t)tok * DIM;
      #pragma unroll
      for (int k = 0; k < 8; k++) {
        float4 a = *(const float4*)(xr + k*32 + q*8);
        float4 c = *(const float4*)(xr + k*32 + q*8 + 4);
        union { bf16x8 v; unsigned short s[8]; } t;
        t.s[0]=f2b(a.x); t.s[1]=f2b(a.y); t.s[2]=f2b(a.z); t.s[3]=f2b(a.w);
        t.s[4]=f2b(c.x); t.s[5]=f2b(c.y); t.s[6]=f2b(c.z); t.s[7]=f2b(c.w);
        xf[m][k] = t.v;
      }
    }

    f32x4 oacc[8][2];
    #pragma unroll
    for (int nt = 0; nt < 8; nt++) { oacc[nt][0] = (f32x4){0,0,0,0}; oacc[nt][1] = (f32x4){0,0,0,0}; }

    // prologue: stage G(0) -> stg[0]
    {
      const char* src = (const char*)wgE;
      char* dst = (char*)stg[0];
      #pragma unroll
      for (int r = 0; r < 4; r++)
        gload_lds16(src + tid*16 + r*4096, dst + tid*16 + r*4096);
    }

    int buf = 0;
    f32x4 ga[2];

    for (int ch = 0; ch < 32; ch++) {
      // ===== G phase =====
      __syncthreads();                       // G(ch) staged; stg[buf^1] free
      { // prefetch U(ch)
        const char* src = (const char*)(wuE + ch*8192);
        char* dst = (char*)stg[buf ^ 1];
        #pragma unroll
        for (int r = 0; r < 4; r++)
          gload_lds16(src + tid*16 + r*4096, dst + tid*16 + r*4096);
      }
      {
        const unsigned short* S = stg[buf];
        ga[0] = (f32x4){0,0,0,0}; ga[1] = (f32x4){0,0,0,0};
        #pragma unroll
        for (int kk = 0; kk < 8; kk++) {
          bf16x8 bg = *(const bf16x8*)&S[guOff + (((kk*4 + q) ^ guXo) << 3)];
          ga[0] = __builtin_amdgcn_mfma_f32_16x16x32_bf16(xf[0][kk], bg, ga[0], 0,0,0);
          ga[1] = __builtin_amdgcn_mfma_f32_16x16x32_bf16(xf[1][kk], bg, ga[1], 0,0,0);
        }
      }
      buf ^= 1;
      // ===== U phase =====
      __syncthreads();                       // U(ch) staged
      { // prefetch D(ch)
        const char* src = (const char*)(wdE + ch*8192);
        char* dst = (char*)stg[buf ^ 1];
        #pragma unroll
        for (int r = 0; r < 4; r++)
          gload_lds16(src + tid*16 + r*4096, dst + tid*16 + r*4096);
      }
      {
        const unsigned short* S = stg[buf];
        f32x4 ua0 = (f32x4){0,0,0,0}, ua1 = (f32x4){0,0,0,0};
        #pragma unroll
        for (int kk = 0; kk < 8; kk++) {
          bf16x8 bu = *(const bf16x8*)&S[guOff + (((kk*4 + q) ^ guXo) << 3)];
          ua0 = __builtin_amdgcn_mfma_f32_16x16x32_bf16(xf[0][kk], bu, ua0, 0,0,0);
          ua1 = __builtin_amdgcn_mfma_f32_16x16x32_bf16(xf[1][kk], bu, ua1, 0,0,0);
        }
        #pragma unroll
        for (int r = 0; r < 4; r++) {
          float g0 = ga[0][r], g1 = ga[1][r];
          hs[mw*32      + q*4 + r][nw*16 + ln] = f2b((g0 / (1.f + __expf(-g0))) * ua0[r]);
          hs[mw*32 + 16 + q*4 + r][nw*16 + ln] = f2b((g1 / (1.f + __expf(-g1))) * ua1[r]);
        }
      }
      buf ^= 1;
      // ===== D phase =====
      __syncthreads();                       // D(ch) staged + hs visible
      if (ch + 1 < 32) { // prefetch G(ch+1)
        const char* src = (const char*)(wgE + (ch+1)*8192);
        char* dst = (char*)stg[buf ^ 1];
        #pragma unroll
        for (int r = 0; r < 4; r++)
          gload_lds16(src + tid*16 + r*4096, dst + tid*16 + r*4096);
      }
      {
        const unsigned short* S = stg[buf];
        bf16x8 a0 = *(const bf16x8*)&hs[mw*32      + ln][q*8];
        bf16x8 a1 = *(const bf16x8*)&hs[mw*32 + 16 + ln][q*8];
        #pragma unroll
        for (int nt = 0; nt < 8; nt++) {
          int d = nw*128 + nt*16 + ln;
          bf16x8 bd = *(const bf16x8*)&S[d*32 + ((q ^ ((d >> 1) & 3)) << 3)];
          oacc[nt][0] = __builtin_amdgcn_mfma_f32_16x16x32_bf16(a0, bd, oacc[nt][0], 0,0,0);
          oacc[nt][1] = __builtin_amdgcn_mfma_f32_16x16x32_bf16(a1, bd, oacc[nt][1], 0,0,0);
        }
      }
      buf ^= 1;
    }

    // epilogue: weighted atomic scatter
    #pragma unroll
    for (int nt = 0; nt < 8; nt++) {
      int d = nw*128 + nt*16 + ln;
      #pragma unroll
      for (int m = 0; m < 2; m++)
        #pragma unroll
        for (int r = 0; r < 4; r++) {
          int tl = mw*32 + m*16 + q*4 + r;
          int tok = lel[tl];
          if (tok >= 0)
            atomicAdd(&out[(size_t)tok*DIM + d], lwt[tl] * oacc[nt][m][r]);
        }
    }
    __syncthreads();   // protect lel/lwt/stg before next tile
  }
}

extern "C" void kernel_launch(void* const* d_in, const int* in_sizes, int n_in,
                              void* d_out, int out_size, void* d_ws, size_t ws_size,
                              hipStream_t stream)
{
  const float* x  = (const float*)d_in[0];
  const float* rw = (const float*)d_in[1];
  const float* wg = (const float*)d_in[2];
  const float* wu = (const float*)d_in[3];
  const float* wd = (const float*)d_in[4];
  float* out = (float*)d_out;

  const size_t W = (size_t)NE * NF * DIM;   // elems per weight tensor
  int*   counts = (int*)d_ws;
  float* psum   = (float*)((char*)d_ws + 128);
  int*   etok   = (int*)((char*)d_ws + 256);
  float* ewt    = (float*)((char*)d_ws + 256 + (size_t)NE*TOK*4);
  unsigned short* wgp = (unsigned short*)((char*)d_ws + 256 + (size_t)NE*TOK*8);
  unsigned short* wup = wgp + W;
  unsigned short* wdp = wup + W;

  hipMemsetAsync(d_ws, 0, 256, stream);
  hipMemsetAsync(d_out, 0, (size_t)out_size * 4, stream);

  router_cvt_kernel<<<256 + 3*2048, 256, 0, stream>>>(
      x, rw, wg, wu, wd, counts, psum, etok, ewt, wgp, wup, wdp);

  expert_mfma6_kernel<<<768, 256, 0, stream>>>(
      x, wgp, wup, wdp, counts, psum, etok, ewt, out);
}